// Round 9
// baseline (291.659 us; speedup 1.0000x reference)
//
#include <hip/hip_runtime.h>

// Generalized Lotka-Volterra, RK4, D=64, batch 2048, 255 steps,
// trajectory out (batch, 256, 64) fp32 — MFMA, zero-shuffle feedback,
// zero-LDS, store-hazard-free.
//
// Per wave: 16 batch elements (p = lane&15 indexes batch). Need-layout:
// lane (g,p) holds x[t][q] = X[batch p][d(t,g,q)], d = 32(t>>1)+8g+4(t&1)+q.
// E_perm rows arranged so MFMA tile t's C-output lands exactly where the
// next B-fragment needs it (verified on HW in rounds 7/8):
//   A[row=p][k=8g+j], B[k=8g+j][col=p], C[row=4g+q][col=p].
// feval: 8 pkrtz -> 8 INDEPENDENT mfma_f32_16x16x32_f16 (two accumulators
// per tile, summed after) -> vector elementwise. Diagonal & r exact fp32.
//
// Round-8 lesson (1800 stall cyc/step at 1 wave/SIMD): the serializers were
//  (a) global stores reading x[] forced per-step vmcnt drains when x is
//      overwritten -> stores now read parity-alternated COPIES (stA/stB,
//      time loop unrolled x2) giving ~2 steps of slack;
//  (b) per-step LDS transpose w/ lgkmcnt(0) memory clobber -> direct
//      dwordx4 stores (tiles 0&1 fill each 128B line; L2 write-combines);
//  (c) chained MFMA C-dependency -> split accumulators.
// State math in f32x4 (v_pk_fma_f32 dual-issue packed f32).

constexpr int D  = 64;    // state dimension
constexpr int NT = 256;   // trajectory length (255 RK4 steps)
constexpr int BW = 16;    // batch elements per wave (MFMA N)

typedef _Float16 f16x8 __attribute__((ext_vector_type(8)));
typedef float    f32x4 __attribute__((ext_vector_type(4)));

__device__ __forceinline__ uint32_t pkrtz(float lo, float hi) {
    return __builtin_bit_cast(uint32_t, __builtin_amdgcn_cvt_pkrtz(lo, hi));
}
__device__ __forceinline__ f32x4 vsplat(float v) {
    return (f32x4){v, v, v, v};
}

// f(XT) = XT .* ((r - XT) + E@XT); XT, F are f32x4[4] in the need-layout.
#define FEVAL(XT, F)                                                          \
    do {                                                                      \
        union { uint32_t u[4]; f16x8 v; } u0_, u1_;                           \
        u0_.u[0] = pkrtz(XT[0][0], XT[0][1]);                                 \
        u0_.u[1] = pkrtz(XT[0][2], XT[0][3]);                                 \
        u0_.u[2] = pkrtz(XT[1][0], XT[1][1]);                                 \
        u0_.u[3] = pkrtz(XT[1][2], XT[1][3]);                                 \
        u1_.u[0] = pkrtz(XT[2][0], XT[2][1]);                                 \
        u1_.u[1] = pkrtz(XT[2][2], XT[2][3]);                                 \
        u1_.u[2] = pkrtz(XT[3][0], XT[3][1]);                                 \
        u1_.u[3] = pkrtz(XT[3][2], XT[3][3]);                                 \
        const f16x8 bf0 = u0_.v, bf1 = u1_.v;                                 \
        _Pragma("unroll")                                                     \
        for (int t_ = 0; t_ < 4; ++t_) {                                      \
            f32x4 c0_ = rl[t_] - XT[t_];                                      \
            f32x4 c1_ = vsplat(0.0f);                                         \
            c0_ = __builtin_amdgcn_mfma_f32_16x16x32_f16(af[t_][0], bf0, c0_, 0, 0, 0); \
            c1_ = __builtin_amdgcn_mfma_f32_16x16x32_f16(af[t_][1], bf1, c1_, 0, 0, 0); \
            F[t_] = XT[t_] * (c0_ + c1_);                                     \
        }                                                                     \
    } while (0)

// One full RK4 step; stores step TS from copy regs ST (parity-alternated).
#define STEP(TS, ST)                                                          \
    do {                                                                      \
        FEVAL(x, k);                                                          \
        _Pragma("unroll")                                                     \
        for (int t_ = 0; t_ < 4; ++t_) {                                      \
            s[t_]   = x[t_] + vsplat(h6) * k[t_];                             \
            xst[t_] = x[t_] + vsplat(h2) * k[t_];                             \
        }                                                                     \
        FEVAL(xst, k);                                                        \
        _Pragma("unroll")                                                     \
        for (int t_ = 0; t_ < 4; ++t_) {                                      \
            s[t_]   = s[t_] + vsplat(2.0f * h6) * k[t_];                      \
            xst[t_] = x[t_] + vsplat(h2) * k[t_];                             \
        }                                                                     \
        FEVAL(xst, k);                                                        \
        _Pragma("unroll")                                                     \
        for (int t_ = 0; t_ < 4; ++t_) {                                      \
            s[t_]   = s[t_] + vsplat(2.0f * h6) * k[t_];                      \
            xst[t_] = x[t_] + vsplat(dt) * k[t_];                             \
        }                                                                     \
        FEVAL(xst, k);                                                        \
        _Pragma("unroll")                                                     \
        for (int t_ = 0; t_ < 4; ++t_) {                                      \
            x[t_]  = s[t_] + vsplat(h6) * k[t_];                              \
            ST[t_] = x[t_];                                                   \
        }                                                                     \
        _Pragma("unroll")                                                     \
        for (int t_ = 0; t_ < 4; ++t_)                                        \
            *reinterpret_cast<f32x4*>(obase + (size_t)(TS) * D + dbase[t_]) = \
                ST[t_];                                                       \
    } while (0)

__global__ __launch_bounds__(64, 1)
void glv_rk4_mfma(const float* __restrict__ x0,
                  const float* __restrict__ r,
                  const float* __restrict__ A,
                  const float* __restrict__ tgrid,
                  float* __restrict__ out)
{
    const int lane = threadIdx.x & 63;
    const int g    = lane >> 4;
    const int p    = lane & 15;
    const int b0   = blockIdx.x * BW;          // first batch elem of this wave

    int dbase[4];
#pragma unroll
    for (int t = 0; t < 4; ++t) dbase[t] = 32 * (t >> 1) + 8 * g + 4 * (t & 1);

    // Stationary A-fragments of permuted E (E = A + I) — layout verified R7/R8.
    f16x8 af[4][2];
#pragma unroll
    for (int t = 0; t < 4; ++t) {
        const int rE = 32 * (t >> 1) + 8 * (p >> 2) + 4 * (t & 1) + (p & 3);
#pragma unroll
        for (int kh = 0; kh < 2; ++kh) {
            const int c0 = 32 * kh + 8 * g;
            const float4 v0 = *reinterpret_cast<const float4*>(A + rE * D + c0);
            const float4 v1 = *reinterpret_cast<const float4*>(A + rE * D + c0 + 4);
            float e[8] = {v0.x, v0.y, v0.z, v0.w, v1.x, v1.y, v1.z, v1.w};
#pragma unroll
            for (int j = 0; j < 8; ++j)
                if (rE == c0 + j) e[j] += 1.0f;
            union { uint32_t u[4]; f16x8 v; } un;
            un.u[0] = pkrtz(e[0], e[1]);
            un.u[1] = pkrtz(e[2], e[3]);
            un.u[2] = pkrtz(e[4], e[5]);
            un.u[3] = pkrtz(e[6], e[7]);
            af[t][kh] = un.v;
        }
    }
    // Anti-sink fence: keep the E fragments register-resident across the loop.
#pragma unroll
    for (int t = 0; t < 4; ++t)
#pragma unroll
        for (int kh = 0; kh < 2; ++kh)
            asm volatile("" : "+v"(af[t][kh]));

    // r and x0 in the need-layout (dbase is a multiple of 4 -> f32x4 loads).
    f32x4 rl[4], x[4];
#pragma unroll
    for (int t = 0; t < 4; ++t) {
        rl[t] = *reinterpret_cast<const f32x4*>(r + dbase[t]);
        x[t]  = *reinterpret_cast<const f32x4*>(x0 + (b0 + p) * D + dbase[t]);
    }

    const float dt = tgrid[1] - tgrid[0];
    const float h2 = 0.5f * dt;
    const float h6 = dt * (1.0f / 6.0f);
    float* const obase = out + (size_t)(b0 + p) * NT * D;

    // t = 0 output is x0.
#pragma unroll
    for (int t = 0; t < 4; ++t)
        *reinterpret_cast<f32x4*>(obase + dbase[t]) = x[t];

    f32x4 s[4], xst[4], k[4], stA[4], stB[4];

    // 255 steps = 127 unrolled pairs + 1; stA/stB parity gives stores ~2
    // steps of slack before their data registers are overwritten.
    for (int ts = 1; ts < NT - 1; ts += 2) {
        STEP(ts, stA);
        STEP(ts + 1, stB);
    }
    STEP(NT - 1, stA);
}

extern "C" void kernel_launch(void* const* d_in, const int* in_sizes, int n_in,
                              void* d_out, int out_size, void* d_ws, size_t ws_size,
                              hipStream_t stream) {
    const float* x0    = (const float*)d_in[0];
    const float* r     = (const float*)d_in[1];
    const float* A     = (const float*)d_in[2];
    const float* tgrid = (const float*)d_in[3];
    float* out         = (float*)d_out;

    const int batch = in_sizes[0] / D;          // 2048
    dim3 grid(batch / BW);                      // 128 one-wave blocks
    dim3 block(64);

    glv_rk4_mfma<<<grid, block, 0, stream>>>(x0, r, A, tgrid, out);
}